// Round 1
// baseline (993.822 us; speedup 1.0000x reference)
//
#include <hip/hip_runtime.h>
#include <math.h>

// ============================================================================
// ChannelAttention (XCA-style) on MI355X — Gram-matrix restructure.
//
//   G_b = X_b^T X_b                       (per-batch 384x384, reduce over 16384 tokens)
//   P1  = Wq G_b, P2 = Wk G_b             (tiny 384^3 GEMMs)
//   ssq_q[c] = <P1[c,:], Wq[c,:]>,  ssq_k likewise (diagonals)
//   S[h]   = head-diagonal 96x96 blocks of P1 Wk^T -> normalize, *temp, softmax -> attn
//   T_b    = blockdiag(attn_b) @ Wv       (384x384)
//   M'_b   = W_out @ T_b                  (384x384)
//   out    = X @ M'_b^T + b_out           (big GEMM, fused bias)
//
// q/k/v are NEVER materialized: ws = 12.4 MB instead of 305 MB, and total
// fp32 work drops from ~82 GF to ~40 GF. All fp32 (no-fp32-MFMA on CDNA4,
// so big GEMMs are vector-ALU 128x128 tiles, 8x8 microtiles).
// ============================================================================

#define B_    4
#define NTOK  16384
#define C_    384
#define NH    4
#define DH    96

// ws layout (float offsets)
#define G_OFF    0
#define G_SZ     (B_*C_*C_)            // 589824
#define P_OFF    (G_OFF + G_SZ)
#define P_SZ     (2*B_*C_*C_)          // 1179648  P[sel][b][c][ck]
#define SSQ_OFF  (P_OFF + P_SZ)
#define SSQ_SZ   (2*B_*C_)             // 3072     ssq[sel][b][c]
#define ATT_OFF  (SSQ_OFF + SSQ_SZ)
#define ATT_SZ   (B_*NH*DH*DH)         // 147456
#define T_OFF    (ATT_OFF + ATT_SZ)
#define T_SZ     (B_*C_*C_)
#define MP_OFF   (T_OFF + T_SZ)

__global__ __launch_bounds__(256) void k_zero(float* __restrict__ p, int n) {
    int i = blockIdx.x * 256 + threadIdx.x;
    if (i < n) p[i] = 0.f;
}

// ---------------------------------------------------------------------------
// G_b += X_chunk^T X_chunk  (tile 128x128, chunk = 1024 tokens, atomic combine)
// grid (16 chunks, 9 tiles, 4 batches), 256 threads
// ---------------------------------------------------------------------------
__global__ __launch_bounds__(256, 2) void k_gram(const float* __restrict__ X,
                                                 float* __restrict__ G) {
    __shared__ float Aa[16][132];
    __shared__ float Ab[16][132];
    const int tid = threadIdx.x;
    const int chunk = blockIdx.x;
    const int ti = blockIdx.y / 3, tj = blockIdx.y % 3;
    const int b = blockIdx.z;
    const int t  = tid >> 4;            // token row 0..15 (loads)
    const int c8 = (tid & 15) * 8;      // col offset (loads)
    const int tm = (tid & 15) * 8, tn = (tid >> 4) * 8;  // compute microtile
    float acc[8][8];
#pragma unroll
    for (int i = 0; i < 8; i++)
#pragma unroll
        for (int j = 0; j < 8; j++) acc[i][j] = 0.f;

    const float* Xb = X + ((size_t)b * NTOK + (size_t)chunk * 1024) * C_;
    for (int s = 0; s < 1024; s += 16) {
        const float* xr = Xb + (size_t)(s + t) * C_;
        float4 a0 = *(const float4*)(xr + ti * 128 + c8);
        float4 a1 = *(const float4*)(xr + ti * 128 + c8 + 4);
        float4 b0 = *(const float4*)(xr + tj * 128 + c8);
        float4 b1 = *(const float4*)(xr + tj * 128 + c8 + 4);
        __syncthreads();
        *(float4*)&Aa[t][c8]     = a0;
        *(float4*)&Aa[t][c8 + 4] = a1;
        *(float4*)&Ab[t][c8]     = b0;
        *(float4*)&Ab[t][c8 + 4] = b1;
        __syncthreads();
#pragma unroll
        for (int k = 0; k < 16; k++) {
            float a[8], bb[8];
            *(float4*)&a[0]  = *(const float4*)&Aa[k][tm];
            *(float4*)&a[4]  = *(const float4*)&Aa[k][tm + 4];
            *(float4*)&bb[0] = *(const float4*)&Ab[k][tn];
            *(float4*)&bb[4] = *(const float4*)&Ab[k][tn + 4];
#pragma unroll
            for (int i = 0; i < 8; i++)
#pragma unroll
                for (int j = 0; j < 8; j++)
                    acc[i][j] = fmaf(a[i], bb[j], acc[i][j]);
        }
    }
    float* Gb = G + (size_t)b * C_ * C_;
#pragma unroll
    for (int i = 0; i < 8; i++)
#pragma unroll
        for (int j = 0; j < 8; j++)
            atomicAdd(&Gb[(size_t)(ti * 128 + tm + i) * C_ + tj * 128 + tn + j],
                      acc[i][j]);
}

// ---------------------------------------------------------------------------
// P[sel][b] = W_{q|k} @ G_b   (C[c][ck] = sum_t W[c][t] * G_b[ck][t], G symm)
// grid (3, 3, 8: z = b*2? -> sel = z&1, b = z>>1), 256 threads
// ---------------------------------------------------------------------------
__global__ __launch_bounds__(256, 2) void k_P(const float* __restrict__ Wqkv,
                                              const float* __restrict__ G,
                                              float* __restrict__ P) {
    __shared__ float As[16][132];
    __shared__ float Bs[16][132];
    const int tid = threadIdx.x;
    const int sel = blockIdx.z & 1, b = blockIdx.z >> 1;
    const int m0 = blockIdx.x * 128, n0 = blockIdx.y * 128;
    const float* A  = Wqkv + (size_t)sel * C_ * C_;
    const float* Bm = G + (size_t)b * C_ * C_;
    const int lr = tid >> 1, lk = (tid & 1) * 8;
    const int tm = (tid & 15) * 8, tn = (tid >> 4) * 8;
    float acc[8][8];
#pragma unroll
    for (int i = 0; i < 8; i++)
#pragma unroll
        for (int j = 0; j < 8; j++) acc[i][j] = 0.f;

    for (int k0 = 0; k0 < C_; k0 += 16) {
        float4 a0 = *(const float4*)(A  + (size_t)(m0 + lr) * C_ + k0 + lk);
        float4 a1 = *(const float4*)(A  + (size_t)(m0 + lr) * C_ + k0 + lk + 4);
        float4 b0 = *(const float4*)(Bm + (size_t)(n0 + lr) * C_ + k0 + lk);
        float4 b1 = *(const float4*)(Bm + (size_t)(n0 + lr) * C_ + k0 + lk + 4);
        __syncthreads();
        As[lk + 0][lr] = a0.x; As[lk + 1][lr] = a0.y; As[lk + 2][lr] = a0.z; As[lk + 3][lr] = a0.w;
        As[lk + 4][lr] = a1.x; As[lk + 5][lr] = a1.y; As[lk + 6][lr] = a1.z; As[lk + 7][lr] = a1.w;
        Bs[lk + 0][lr] = b0.x; Bs[lk + 1][lr] = b0.y; Bs[lk + 2][lr] = b0.z; Bs[lk + 3][lr] = b0.w;
        Bs[lk + 4][lr] = b1.x; Bs[lk + 5][lr] = b1.y; Bs[lk + 6][lr] = b1.z; Bs[lk + 7][lr] = b1.w;
        __syncthreads();
#pragma unroll
        for (int k = 0; k < 16; k++) {
            float a[8], bb[8];
            *(float4*)&a[0]  = *(const float4*)&As[k][tm];
            *(float4*)&a[4]  = *(const float4*)&As[k][tm + 4];
            *(float4*)&bb[0] = *(const float4*)&Bs[k][tn];
            *(float4*)&bb[4] = *(const float4*)&Bs[k][tn + 4];
#pragma unroll
            for (int i = 0; i < 8; i++)
#pragma unroll
                for (int j = 0; j < 8; j++)
                    acc[i][j] = fmaf(a[i], bb[j], acc[i][j]);
        }
    }
    float* out = P + ((size_t)(sel * B_ + b) * C_ + m0 + tm) * C_ + n0 + tn;
#pragma unroll
    for (int i = 0; i < 8; i++) {
        float4 c0 = make_float4(acc[i][0], acc[i][1], acc[i][2], acc[i][3]);
        float4 c1 = make_float4(acc[i][4], acc[i][5], acc[i][6], acc[i][7]);
        *(float4*)(out + (size_t)i * C_)     = c0;
        *(float4*)(out + (size_t)i * C_ + 4) = c1;
    }
}

// ---------------------------------------------------------------------------
// ssq[sel][b][c] = <P[sel][b][c][:], W_{sel}[c][:]>   (3072 dots of length 384)
// ---------------------------------------------------------------------------
__global__ __launch_bounds__(256) void k_diag(const float* __restrict__ P,
                                              const float* __restrict__ Wqkv,
                                              float* __restrict__ ssq) {
    int g = blockIdx.x * 256 + threadIdx.x;   // 0..3071, grid = 12 exact
    int sel = g / (B_ * C_), rem = g % (B_ * C_), b = rem / C_, c = rem % C_;
    const float* pr = P + ((size_t)(sel * B_ + b) * C_ + c) * C_;
    const float* wr = Wqkv + ((size_t)sel * C_ + c) * C_;
    float s = 0.f;
#pragma unroll 4
    for (int k = 0; k < C_; k += 4) {
        float4 pv = *(const float4*)(pr + k);
        float4 wv = *(const float4*)(wr + k);
        s += pv.x * wv.x + pv.y * wv.y + pv.z * wv.z + pv.w * wv.w;
    }
    ssq[g] = s;
}

// ---------------------------------------------------------------------------
// attn[b][h] = softmax_d( (P1 Wk^T)[96x96 head block] / (nq nk) * temp[h] )
// one block per (b,h), 256 threads; 6x6 microtile over 96x96
// ---------------------------------------------------------------------------
__global__ __launch_bounds__(256) void k_attn(const float* __restrict__ P,
                                              const float* __restrict__ Wqkv,
                                              const float* __restrict__ ssq,
                                              const float* __restrict__ temp,
                                              float* __restrict__ attn) {
    __shared__ float sm[DH * 97];              // phase1: Ps[32][97]+Ks[32][97]; phase2: St[96][97]
    const int bh = blockIdx.x;
    const int b = bh >> 2, h = bh & 3;
    const int tid = threadIdx.x;
    const int ti = tid & 15, tj = tid >> 4;
    float acc[6][6];
#pragma unroll
    for (int i = 0; i < 6; i++)
#pragma unroll
        for (int j = 0; j < 6; j++) acc[i][j] = 0.f;

    const float* P1 = P + ((size_t)b * C_ + h * DH) * C_;          // sel=0 rows
    const float* Wk = Wqkv + ((size_t)(C_ + h * DH)) * C_;         // k-weight rows
    float* Ps = sm;
    float* Ks = sm + 32 * 97;

    for (int k0 = 0; k0 < C_; k0 += 32) {
        __syncthreads();
#pragma unroll
        for (int j = 0; j < 3; j++) {
            int f = tid + 256 * j;             // 0..767
            int row = f >> 3, q = f & 7;       // row 0..95, 4-float group 0..7
            float4 v = *(const float4*)(P1 + (size_t)row * C_ + k0 + q * 4);
            Ps[(q * 4 + 0) * 97 + row] = v.x;
            Ps[(q * 4 + 1) * 97 + row] = v.y;
            Ps[(q * 4 + 2) * 97 + row] = v.z;
            Ps[(q * 4 + 3) * 97 + row] = v.w;
            float4 w = *(const float4*)(Wk + (size_t)row * C_ + k0 + q * 4);
            Ks[(q * 4 + 0) * 97 + row] = w.x;
            Ks[(q * 4 + 1) * 97 + row] = w.y;
            Ks[(q * 4 + 2) * 97 + row] = w.z;
            Ks[(q * 4 + 3) * 97 + row] = w.w;
        }
        __syncthreads();
#pragma unroll
        for (int k = 0; k < 32; k++) {
            float a[6], bb[6];
#pragma unroll
            for (int i = 0; i < 6; i++) a[i]  = Ps[k * 97 + ti * 6 + i];
#pragma unroll
            for (int j = 0; j < 6; j++) bb[j] = Ks[k * 97 + tj * 6 + j];
#pragma unroll
            for (int i = 0; i < 6; i++)
#pragma unroll
                for (int j = 0; j < 6; j++)
                    acc[i][j] = fmaf(a[i], bb[j], acc[i][j]);
        }
    }
    // normalize by L2 norms + temperature, park in LDS
    float tpr = temp[h];
    float nq[6], nk[6];
#pragma unroll
    for (int i = 0; i < 6; i++)
        nq[i] = fmaxf(sqrtf(ssq[b * C_ + h * DH + ti * 6 + i]), 1e-12f);
#pragma unroll
    for (int j = 0; j < 6; j++)
        nk[j] = fmaxf(sqrtf(ssq[B_ * C_ + b * C_ + h * DH + tj * 6 + j]), 1e-12f);
    __syncthreads();
#pragma unroll
    for (int i = 0; i < 6; i++)
#pragma unroll
        for (int j = 0; j < 6; j++)
            sm[(ti * 6 + i) * 97 + tj * 6 + j] = acc[i][j] / (nq[i] * nk[j]) * tpr;
    __syncthreads();
    // row softmax (threads 0..95 each own one row)
    if (tid < DH) {
        float* row = sm + tid * 97;
        float m = -1e30f;
        for (int d = 0; d < DH; d++) m = fmaxf(m, row[d]);
        float ssum = 0.f;
        for (int d = 0; d < DH; d++) { float e = __expf(row[d] - m); row[d] = e; ssum += e; }
        float inv = 1.f / ssum;
        float* arow = attn + ((size_t)bh * DH + tid) * DH;
        for (int d = 0; d < DH; d++) arow[d] = row[d] * inv;
    }
}

// ---------------------------------------------------------------------------
// T_b[(h,c)][ck] = sum_d attn[b][h][c][d] * Wv[(h,d)][ck]
// grid (3, 1536), 128 threads (lane = ck within 128-block)
// ---------------------------------------------------------------------------
__global__ __launch_bounds__(128) void k_T(const float* __restrict__ attn,
                                           const float* __restrict__ Wqkv,
                                           float* __restrict__ T) {
    const int ck = blockIdx.x * 128 + threadIdx.x;
    const int y = blockIdx.y;                  // b*384 + h*96 + c
    const int b = y / C_, hc = y % C_, h = hc / DH, c = hc % DH;
    const float* ar = attn + ((size_t)(b * NH + h) * DH + c) * DH;
    const float* wv = Wqkv + ((size_t)(2 * C_ + h * DH)) * C_ + ck;
    float s = 0.f;
#pragma unroll 8
    for (int d = 0; d < DH; d++) s = fmaf(ar[d], wv[(size_t)d * C_], s);
    T[((size_t)b * C_ + hc) * C_ + ck] = s;
}

// ---------------------------------------------------------------------------
// M'_b[i][ck] = sum_kk W_out[i][kk] * T_b[kk][ck]   grid (3,3,4)
// ---------------------------------------------------------------------------
__global__ __launch_bounds__(256, 2) void k_Mp(const float* __restrict__ Wout,
                                               const float* __restrict__ T,
                                               float* __restrict__ Mp) {
    __shared__ float As[16][132];   // As[kk][i]
    __shared__ float Bs[16][132];   // Bs[kk][ck]
    const int tid = threadIdx.x;
    const int b = blockIdx.z;
    const int m0 = blockIdx.x * 128, n0 = blockIdx.y * 128;
    const int lr = tid >> 1, lk = (tid & 1) * 8;        // A loads
    const int rt = tid >> 4, rc8 = (tid & 15) * 8;      // B loads
    const int tm = (tid & 15) * 8, tn = (tid >> 4) * 8;
    const float* Tb = T + (size_t)b * C_ * C_;
    float acc[8][8];
#pragma unroll
    for (int i = 0; i < 8; i++)
#pragma unroll
        for (int j = 0; j < 8; j++) acc[i][j] = 0.f;

    for (int k0 = 0; k0 < C_; k0 += 16) {
        float4 a0 = *(const float4*)(Wout + (size_t)(m0 + lr) * C_ + k0 + lk);
        float4 a1 = *(const float4*)(Wout + (size_t)(m0 + lr) * C_ + k0 + lk + 4);
        float4 b0 = *(const float4*)(Tb + (size_t)(k0 + rt) * C_ + n0 + rc8);
        float4 b1 = *(const float4*)(Tb + (size_t)(k0 + rt) * C_ + n0 + rc8 + 4);
        __syncthreads();
        As[lk + 0][lr] = a0.x; As[lk + 1][lr] = a0.y; As[lk + 2][lr] = a0.z; As[lk + 3][lr] = a0.w;
        As[lk + 4][lr] = a1.x; As[lk + 5][lr] = a1.y; As[lk + 6][lr] = a1.z; As[lk + 7][lr] = a1.w;
        *(float4*)&Bs[rt][rc8]     = b0;
        *(float4*)&Bs[rt][rc8 + 4] = b1;
        __syncthreads();
#pragma unroll
        for (int k = 0; k < 16; k++) {
            float a[8], bb[8];
            *(float4*)&a[0]  = *(const float4*)&As[k][tm];
            *(float4*)&a[4]  = *(const float4*)&As[k][tm + 4];
            *(float4*)&bb[0] = *(const float4*)&Bs[k][tn];
            *(float4*)&bb[4] = *(const float4*)&Bs[k][tn + 4];
#pragma unroll
            for (int i = 0; i < 8; i++)
#pragma unroll
                for (int j = 0; j < 8; j++)
                    acc[i][j] = fmaf(a[i], bb[j], acc[i][j]);
        }
    }
    float* out = Mp + ((size_t)b * C_ + m0 + tm) * C_ + n0 + tn;
#pragma unroll
    for (int i = 0; i < 8; i++) {
        float4 c0 = make_float4(acc[i][0], acc[i][1], acc[i][2], acc[i][3]);
        float4 c1 = make_float4(acc[i][4], acc[i][5], acc[i][6], acc[i][7]);
        *(float4*)(out + (size_t)i * C_)     = c0;
        *(float4*)(out + (size_t)i * C_ + 4) = c1;
    }
}

// ---------------------------------------------------------------------------
// out[m][i] = sum_ck X[m][ck] * M'_b[i][ck] + bias[i]    grid (512, 3)
// ---------------------------------------------------------------------------
__global__ __launch_bounds__(256, 2) void k_out(const float* __restrict__ X,
                                                const float* __restrict__ Mp,
                                                const float* __restrict__ bias,
                                                float* __restrict__ out) {
    __shared__ float As[16][132];
    __shared__ float Bs[16][132];
    const int tid = threadIdx.x;
    const int m0 = blockIdx.x * 128, n0 = blockIdx.y * 128;
    const int b = m0 / NTOK;
    const float* Mb = Mp + (size_t)b * C_ * C_;
    const int lr = tid >> 1, lk = (tid & 1) * 8;
    const int tm = (tid & 15) * 8, tn = (tid >> 4) * 8;
    float acc[8][8];
#pragma unroll
    for (int i = 0; i < 8; i++)
#pragma unroll
        for (int j = 0; j < 8; j++) acc[i][j] = 0.f;

    for (int k0 = 0; k0 < C_; k0 += 16) {
        float4 a0 = *(const float4*)(X  + (size_t)(m0 + lr) * C_ + k0 + lk);
        float4 a1 = *(const float4*)(X  + (size_t)(m0 + lr) * C_ + k0 + lk + 4);
        float4 b0 = *(const float4*)(Mb + (size_t)(n0 + lr) * C_ + k0 + lk);
        float4 b1 = *(const float4*)(Mb + (size_t)(n0 + lr) * C_ + k0 + lk + 4);
        __syncthreads();
        As[lk + 0][lr] = a0.x; As[lk + 1][lr] = a0.y; As[lk + 2][lr] = a0.z; As[lk + 3][lr] = a0.w;
        As[lk + 4][lr] = a1.x; As[lk + 5][lr] = a1.y; As[lk + 6][lr] = a1.z; As[lk + 7][lr] = a1.w;
        Bs[lk + 0][lr] = b0.x; Bs[lk + 1][lr] = b0.y; Bs[lk + 2][lr] = b0.z; Bs[lk + 3][lr] = b0.w;
        Bs[lk + 4][lr] = b1.x; Bs[lk + 5][lr] = b1.y; Bs[lk + 6][lr] = b1.z; Bs[lk + 7][lr] = b1.w;
        __syncthreads();
#pragma unroll
        for (int k = 0; k < 16; k++) {
            float a[8], bb[8];
            *(float4*)&a[0]  = *(const float4*)&As[k][tm];
            *(float4*)&a[4]  = *(const float4*)&As[k][tm + 4];
            *(float4*)&bb[0] = *(const float4*)&Bs[k][tn];
            *(float4*)&bb[4] = *(const float4*)&Bs[k][tn + 4];
#pragma unroll
            for (int i = 0; i < 8; i++)
#pragma unroll
                for (int j = 0; j < 8; j++)
                    acc[i][j] = fmaf(a[i], bb[j], acc[i][j]);
        }
    }
#pragma unroll
    for (int i = 0; i < 8; i++) {
        float4 c0 = make_float4(acc[i][0] + bias[n0 + tn + 0],
                                acc[i][1] + bias[n0 + tn + 1],
                                acc[i][2] + bias[n0 + tn + 2],
                                acc[i][3] + bias[n0 + tn + 3]);
        float4 c1 = make_float4(acc[i][4] + bias[n0 + tn + 4],
                                acc[i][5] + bias[n0 + tn + 5],
                                acc[i][6] + bias[n0 + tn + 6],
                                acc[i][7] + bias[n0 + tn + 7]);
        float* row = out + (size_t)(m0 + tm + i) * C_ + n0 + tn;
        *(float4*)row       = c0;
        *(float4*)(row + 4) = c1;
    }
}

extern "C" void kernel_launch(void* const* d_in, const int* in_sizes, int n_in,
                              void* d_out, int out_size, void* d_ws, size_t ws_size,
                              hipStream_t stream) {
    const float* x    = (const float*)d_in[0];   // (4,16384,384)
    const float* Wqkv = (const float*)d_in[1];   // (1152,384)
    const float* temp = (const float*)d_in[2];   // (4,1,1)
    const float* Wout = (const float*)d_in[3];   // (384,384)
    const float* bout = (const float*)d_in[4];   // (384,)
    float* out = (float*)d_out;
    float* ws  = (float*)d_ws;

    float* G    = ws + G_OFF;
    float* P    = ws + P_OFF;
    float* ssq  = ws + SSQ_OFF;
    float* attn = ws + ATT_OFF;
    float* T    = ws + T_OFF;
    float* Mp   = ws + MP_OFF;

    // ws is re-poisoned to 0xAA before every launch: G must be zeroed (atomics)
    k_zero<<<dim3(G_SZ / 256), 256, 0, stream>>>(G, G_SZ);
    k_gram<<<dim3(16, 9, B_), 256, 0, stream>>>(x, G);
    k_P   <<<dim3(3, 3, 2 * B_), 256, 0, stream>>>(Wqkv, G, P);
    k_diag<<<dim3(12), 256, 0, stream>>>(P, Wqkv, ssq);
    k_attn<<<dim3(B_ * NH), 256, 0, stream>>>(P, Wqkv, ssq, temp, attn);
    k_T   <<<dim3(3, B_ * C_), 128, 0, stream>>>(attn, Wqkv, T);
    k_Mp  <<<dim3(3, 3, B_), 256, 0, stream>>>(Wout, T, Mp);
    k_out <<<dim3(NTOK * B_ / 128, 3), 256, 0, stream>>>(x, Mp, bout, out);
}

// Round 3
// 473.094 us; speedup vs baseline: 2.1007x; 2.1007x over previous
//
#include <hip/hip_runtime.h>
#include <math.h>

// ============================================================================
// ChannelAttention — Gram restructure + bf16 MFMA for the two big GEMMs.
//
//   k_conv:   X(fp32) -> Xh [b][t][c] bf16  and  XhT [b][c][t] bf16
//   k_gram:   Gpart[chunk] = XhT-tile @ XhT-tile^T (MFMA 16x16x32, no atomics)
//   k_reduce: G = sum_chunk Gpart
//   k_P/k_diag/k_attn/k_T/k_Mp: unchanged fp32 small chain
//   k_convM:  Mp -> Mph bf16
//   k_out:    out = Xh @ Mph^T + bias (MFMA)
//
// Pure-bf16 inputs (no hi/lo split): adds ~1e-5 error vs the 4.9e-4 fp32
// baseline absmax (errors cancel over K=16384 / K=384).
// Gated on ws_size >= 152 MB; falls back to the proven round-1 fp32 path.
// ============================================================================

#define B_    4
#define NTOK  16384
#define C_    384
#define NH    4
#define DH    96

typedef __attribute__((ext_vector_type(8))) short short8;
typedef __attribute__((ext_vector_type(4))) float f32x4;
typedef __attribute__((ext_vector_type(4))) unsigned short ushort4v;
typedef __attribute__((ext_vector_type(8))) unsigned short ushort8v;

// ---- big-path ws byte offsets ----
#define XH_B   0ull
#define XHT_B  50331648ull            // + B*N*C*2
#define GP_B   100663296ull           // 16 chunk partials x 4 batches, fp32
#define G_B    138412032ull
#define P_B    140771328ull
#define SSQ_B  145489920ull
#define ATT_B  145502208ull
#define T_B    146092032ull
#define MP_B   148451328ull
#define MPH_B  150810624ull
#define WS_NEED 151990272ull

// ---- fallback (round-1) ws float offsets ----
#define FG_OFF    0
#define FG_SZ     (B_*C_*C_)
#define FP_OFF    (FG_OFF + FG_SZ)
#define FP_SZ     (2*B_*C_*C_)
#define FSSQ_OFF  (FP_OFF + FP_SZ)
#define FSSQ_SZ   (2*B_*C_)
#define FATT_OFF  (FSSQ_OFF + FSSQ_SZ)
#define FATT_SZ   (B_*NH*DH*DH)
#define FT_OFF    (FATT_OFF + FATT_SZ)
#define FT_SZ     (B_*C_*C_)
#define FMP_OFF   (FT_OFF + FT_SZ)

__device__ inline unsigned short f2bf(float f) {
    unsigned u = __float_as_uint(f);
    u += 0x7FFFu + ((u >> 16) & 1u);          // RNE
    return (unsigned short)(u >> 16);
}

__device__ inline void load16(const void* g, void* l) {
    __builtin_amdgcn_global_load_lds(
        (const __attribute__((address_space(1))) unsigned int*)g,
        (__attribute__((address_space(3))) unsigned int*)l, 16, 0, 0);
}

// ---------------------------------------------------------------------------
// X fp32 -> Xh (natural) + XhT (transposed) bf16.  64x64 tiles via LDS.
// grid (256, 6, 4), 256 threads
// ---------------------------------------------------------------------------
__global__ __launch_bounds__(256) void k_conv(const float* __restrict__ X,
                                              unsigned short* __restrict__ Xh,
                                              unsigned short* __restrict__ XhT) {
    __shared__ __align__(16) unsigned short Th[64][72];
    const int tid = threadIdx.x;
    const int t0 = blockIdx.x * 64, c0 = blockIdx.y * 64, b = blockIdx.z;
    const int tl0 = tid >> 4, cl = (tid & 15) * 4;
#pragma unroll
    for (int p = 0; p < 4; ++p) {
        const int t = t0 + tl0 + p * 16;
        const float4 v = *(const float4*)(X + ((size_t)(b * NTOK + t)) * C_ + c0 + cl);
        const unsigned short h0 = f2bf(v.x), h1 = f2bf(v.y), h2 = f2bf(v.z), h3 = f2bf(v.w);
        ushort4v hv; hv.x = h0; hv.y = h1; hv.z = h2; hv.w = h3;
        *(ushort4v*)(Xh + ((size_t)(b * NTOK + t)) * C_ + c0 + cl) = hv;
        const int tl = tl0 + p * 16;
        Th[cl + 0][tl] = h0; Th[cl + 1][tl] = h1; Th[cl + 2][tl] = h2; Th[cl + 3][tl] = h3;
    }
    __syncthreads();
    const int c = tid >> 2, seg = (tid & 3) * 16;
    const ushort8v a  = *(const ushort8v*)&Th[c][seg];
    const ushort8v bb = *(const ushort8v*)&Th[c][seg + 8];
    unsigned short* dst = XhT + ((size_t)(b * C_ + c0 + c)) * NTOK + t0 + seg;
    *(ushort8v*)dst       = a;
    *(ushort8v*)(dst + 8) = bb;
}

// ---------------------------------------------------------------------------
// Gpart[grp] tile(i,j) 128x128 over a 1024-token chunk.  MFMA 16x16x32 bf16.
// 576 blocks (XCD-grouped: 9 tiles of one (chunk,b) share an XCD's L2),
// 256 threads = 4 waves of 64x64.
// ---------------------------------------------------------------------------
__global__ __launch_bounds__(256, 2) void k_gram_mfma(const unsigned short* __restrict__ XhT,
                                                      float* __restrict__ Gpart) {
    __shared__ __align__(16) unsigned char sm[32768];   // A rows [0,16K), B rows [16K,32K)
    const int l = blockIdx.x;
    const int xcd = l & 7, slot = l >> 3;
    const int grp = xcd * 8 + slot / 9, tile = slot % 9;  // grp = chunk*4 + b
    const int chunk = grp >> 2, b = grp & 3;
    const int ti = tile / 3, tj = tile % 3;
    const int tid = threadIdx.x;
    const int lane = tid & 63, wid = tid >> 6;
    const int wr = wid >> 1, wc = wid & 1;

    const int e = (lane & 7) ^ (lane >> 3);   // inverse-swizzled source slot (rule 21)
    const int rsub = lane >> 3;

    const size_t rowb = (size_t)NTOK * 2;
    const unsigned char* Abase = (const unsigned char*)XhT + (size_t)(b * C_ + ti * 128) * rowb;
    const unsigned char* Bbase = (const unsigned char*)XhT + (size_t)(b * C_ + tj * 128) * rowb;

    f32x4 acc[4][4];
#pragma unroll
    for (int i = 0; i < 4; i++)
#pragma unroll
        for (int j = 0; j < 4; j++) acc[i][j] = (f32x4)(0.f);

    for (int ks = 0; ks < 16; ++ks) {
        const size_t colb = (size_t)(chunk * 1024 + ks * 64) * 2 + (size_t)e * 16;
        __syncthreads();
#pragma unroll
        for (int call = 0; call < 4; ++call) {
            const int row = wid * 32 + call * 8 + rsub;
            load16(Abase + (size_t)row * rowb + colb, sm + (wid * 32 + call * 8) * 128);
            load16(Bbase + (size_t)row * rowb + colb, sm + 16384 + (wid * 32 + call * 8) * 128);
        }
        __syncthreads();
#pragma unroll
        for (int p = 0; p < 2; ++p) {
            const int s = p * 4 + (lane >> 4);
            short8 av[4], bv[4];
#pragma unroll
            for (int fi = 0; fi < 4; ++fi) {
                const int c = wr * 64 + fi * 16 + (lane & 15);
                av[fi] = *(const short8*)(sm + c * 128 + ((s ^ (c & 7)) << 4));
            }
#pragma unroll
            for (int fj = 0; fj < 4; ++fj) {
                const int c = wc * 64 + fj * 16 + (lane & 15);
                bv[fj] = *(const short8*)(sm + 16384 + c * 128 + ((s ^ (c & 7)) << 4));
            }
#pragma unroll
            for (int fi = 0; fi < 4; ++fi)
#pragma unroll
                for (int fj = 0; fj < 4; ++fj)
                    acc[fi][fj] = __builtin_amdgcn_mfma_f32_16x16x32_bf16(av[fi], bv[fj], acc[fi][fj], 0, 0, 0);
        }
    }
    // D layout (m89): col = lane&15, row = (lane>>4)*4 + reg
    float* gp = Gpart + (size_t)grp * (C_ * C_);
    const int r0 = (lane >> 4) * 4, cc = lane & 15;
#pragma unroll
    for (int fi = 0; fi < 4; ++fi) {
        const int ci = ti * 128 + wr * 64 + fi * 16 + r0;
#pragma unroll
        for (int fj = 0; fj < 4; ++fj) {
            const int cj = tj * 128 + wc * 64 + fj * 16 + cc;
#pragma unroll
            for (int r = 0; r < 4; ++r)
                gp[(size_t)(ci + r) * C_ + cj] = acc[fi][fj][r];
        }
    }
}

__global__ __launch_bounds__(256) void k_reduceG(const float* __restrict__ Gpart,
                                                 float* __restrict__ G) {
    const size_t eo = ((size_t)blockIdx.x * 256 + threadIdx.x) * 4;
    float4 s = *(const float4*)(Gpart + eo);
#pragma unroll
    for (int c = 1; c < 16; ++c) {
        const float4 v = *(const float4*)(Gpart + (size_t)c * (B_ * C_ * C_) + eo);
        s.x += v.x; s.y += v.y; s.z += v.z; s.w += v.w;
    }
    *(float4*)(G + eo) = s;
}

__global__ __launch_bounds__(256) void k_convM(const float* __restrict__ Mp,
                                               unsigned short* __restrict__ Mph) {
    const size_t eo = ((size_t)blockIdx.x * 256 + threadIdx.x) * 4;
    const float4 v = *(const float4*)(Mp + eo);
    ushort4v h; h.x = f2bf(v.x); h.y = f2bf(v.y); h.z = f2bf(v.z); h.w = f2bf(v.w);
    *(ushort4v*)(Mph + eo) = h;
}

// ---------------------------------------------------------------------------
// out[m][i] = sum_ck Xh[m][ck]*Mph[b][i][ck] + bias[i].  MFMA, K=384.
// 1536 blocks (1-D, XCD-grouped so the 3 i-tiles of one m-tile co-reside),
// 256 threads = 4 waves of 64x64.
// ---------------------------------------------------------------------------
__global__ __launch_bounds__(256, 2) void k_out_mfma(const unsigned short* __restrict__ Xh,
                                                     const unsigned short* __restrict__ Mph,
                                                     const float* __restrict__ bias,
                                                     float* __restrict__ out) {
    __shared__ __align__(16) unsigned char sm[32768];
    const int l = blockIdx.x;
    const int xcd = l & 7, k = l >> 3;
    const int mblk = xcd * 64 + k / 3, nblk = k % 3;
    const int m0 = mblk * 128, i0 = nblk * 128;
    const int b = mblk >> 7;
    const int tid = threadIdx.x;
    const int lane = tid & 63, wid = tid >> 6;
    const int wr = wid >> 1, wc = wid & 1;

    const int e = (lane & 7) ^ (lane >> 3);
    const int rsub = lane >> 3;

    const unsigned char* Abase = (const unsigned char*)Xh + (size_t)m0 * (C_ * 2);
    const unsigned char* Bbase = (const unsigned char*)Mph + (size_t)b * (C_ * C_ * 2) + (size_t)i0 * (C_ * 2);

    f32x4 acc[4][4];
#pragma unroll
    for (int i = 0; i < 4; i++)
#pragma unroll
        for (int j = 0; j < 4; j++) acc[i][j] = (f32x4)(0.f);

    for (int ks = 0; ks < 6; ++ks) {
        const size_t colb = (size_t)ks * 128 + (size_t)e * 16;
        __syncthreads();
#pragma unroll
        for (int call = 0; call < 4; ++call) {
            const int row = wid * 32 + call * 8 + rsub;
            load16(Abase + (size_t)row * (C_ * 2) + colb, sm + (wid * 32 + call * 8) * 128);
            load16(Bbase + (size_t)row * (C_ * 2) + colb, sm + 16384 + (wid * 32 + call * 8) * 128);
        }
        __syncthreads();
#pragma unroll
        for (int p = 0; p < 2; ++p) {
            const int s = p * 4 + (lane >> 4);
            short8 av[4], bv[4];
#pragma unroll
            for (int fi = 0; fi < 4; ++fi) {
                const int c = wr * 64 + fi * 16 + (lane & 15);
                av[fi] = *(const short8*)(sm + c * 128 + ((s ^ (c & 7)) << 4));
            }
#pragma unroll
            for (int fj = 0; fj < 4; ++fj) {
                const int c = wc * 64 + fj * 16 + (lane & 15);
                bv[fj] = *(const short8*)(sm + 16384 + c * 128 + ((s ^ (c & 7)) << 4));
            }
#pragma unroll
            for (int fi = 0; fi < 4; ++fi)
#pragma unroll
                for (int fj = 0; fj < 4; ++fj)
                    acc[fi][fj] = __builtin_amdgcn_mfma_f32_16x16x32_bf16(av[fi], bv[fj], acc[fi][fj], 0, 0, 0);
        }
    }
    const int r0 = (lane >> 4) * 4, cc = lane & 15;
#pragma unroll
    for (int fi = 0; fi < 4; ++fi) {
        const int m = m0 + wr * 64 + fi * 16 + r0;
#pragma unroll
        for (int fj = 0; fj < 4; ++fj) {
            const int ii = i0 + wc * 64 + fj * 16 + cc;
            const float bi = bias[ii];
#pragma unroll
            for (int r = 0; r < 4; ++r)
                out[(size_t)(m + r) * C_ + ii] = acc[fi][fj][r] + bi;
        }
    }
}

// ===========================================================================
// Shared fp32 small-kernel chain (unchanged from round 1, proven correct)
// ===========================================================================
__global__ __launch_bounds__(256) void k_zero(float* __restrict__ p, int n) {
    int i = blockIdx.x * 256 + threadIdx.x;
    if (i < n) p[i] = 0.f;
}

__global__ __launch_bounds__(256, 2) void k_P(const float* __restrict__ Wqkv,
                                              const float* __restrict__ G,
                                              float* __restrict__ P) {
    __shared__ float As[16][132];
    __shared__ float Bs[16][132];
    const int tid = threadIdx.x;
    const int sel = blockIdx.z & 1, b = blockIdx.z >> 1;
    const int m0 = blockIdx.x * 128, n0 = blockIdx.y * 128;
    const float* A  = Wqkv + (size_t)sel * C_ * C_;
    const float* Bm = G + (size_t)b * C_ * C_;
    const int lr = tid >> 1, lk = (tid & 1) * 8;
    const int tm = (tid & 15) * 8, tn = (tid >> 4) * 8;
    float acc[8][8];
#pragma unroll
    for (int i = 0; i < 8; i++)
#pragma unroll
        for (int j = 0; j < 8; j++) acc[i][j] = 0.f;

    for (int k0 = 0; k0 < C_; k0 += 16) {
        float4 a0 = *(const float4*)(A  + (size_t)(m0 + lr) * C_ + k0 + lk);
        float4 a1 = *(const float4*)(A  + (size_t)(m0 + lr) * C_ + k0 + lk + 4);
        float4 b0 = *(const float4*)(Bm + (size_t)(n0 + lr) * C_ + k0 + lk);
        float4 b1 = *(const float4*)(Bm + (size_t)(n0 + lr) * C_ + k0 + lk + 4);
        __syncthreads();
        As[lk + 0][lr] = a0.x; As[lk + 1][lr] = a0.y; As[lk + 2][lr] = a0.z; As[lk + 3][lr] = a0.w;
        As[lk + 4][lr] = a1.x; As[lk + 5][lr] = a1.y; As[lk + 6][lr] = a1.z; As[lk + 7][lr] = a1.w;
        Bs[lk + 0][lr] = b0.x; Bs[lk + 1][lr] = b0.y; Bs[lk + 2][lr] = b0.z; Bs[lk + 3][lr] = b0.w;
        Bs[lk + 4][lr] = b1.x; Bs[lk + 5][lr] = b1.y; Bs[lk + 6][lr] = b1.z; Bs[lk + 7][lr] = b1.w;
        __syncthreads();
#pragma unroll
        for (int k = 0; k < 16; k++) {
            float a[8], bb[8];
            *(float4*)&a[0]  = *(const float4*)&As[k][tm];
            *(float4*)&a[4]  = *(const float4*)&As[k][tm + 4];
            *(float4*)&bb[0] = *(const float4*)&Bs[k][tn];
            *(float4*)&bb[4] = *(const float4*)&Bs[k][tn + 4];
#pragma unroll
            for (int i = 0; i < 8; i++)
#pragma unroll
                for (int j = 0; j < 8; j++)
                    acc[i][j] = fmaf(a[i], bb[j], acc[i][j]);
        }
    }
    float* outp = P + ((size_t)(sel * B_ + b) * C_ + m0 + tm) * C_ + n0 + tn;
#pragma unroll
    for (int i = 0; i < 8; i++) {
        float4 c0 = make_float4(acc[i][0], acc[i][1], acc[i][2], acc[i][3]);
        float4 c1 = make_float4(acc[i][4], acc[i][5], acc[i][6], acc[i][7]);
        *(float4*)(outp + (size_t)i * C_)     = c0;
        *(float4*)(outp + (size_t)i * C_ + 4) = c1;
    }
}

__global__ __launch_bounds__(256) void k_diag(const float* __restrict__ P,
                                              const float* __restrict__ Wqkv,
                                              float* __restrict__ ssq) {
    int g = blockIdx.x * 256 + threadIdx.x;
    int sel = g / (B_ * C_), rem = g % (B_ * C_), b = rem / C_, c = rem % C_;
    const float* pr = P + ((size_t)(sel * B_ + b) * C_ + c) * C_;
    const float* wr = Wqkv + ((size_t)sel * C_ + c) * C_;
    float s = 0.f;
#pragma unroll 4
    for (int k = 0; k < C_; k += 4) {
        float4 pv = *(const float4*)(pr + k);
        float4 wv = *(const float4*)(wr + k);
        s += pv.x * wv.x + pv.y * wv.y + pv.z * wv.z + pv.w * wv.w;
    }
    ssq[g] = s;
}

__global__ __launch_bounds__(256) void k_attn(const float* __restrict__ P,
                                              const float* __restrict__ Wqkv,
                                              const float* __restrict__ ssq,
                                              const float* __restrict__ temp,
                                              float* __restrict__ attn) {
    __shared__ float smb[DH * 97];
    const int bh = blockIdx.x;
    const int b = bh >> 2, h = bh & 3;
    const int tid = threadIdx.x;
    const int ti = tid & 15, tj = tid >> 4;
    float acc[6][6];
#pragma unroll
    for (int i = 0; i < 6; i++)
#pragma unroll
        for (int j = 0; j < 6; j++) acc[i][j] = 0.f;

    const float* P1 = P + ((size_t)b * C_ + h * DH) * C_;
    const float* Wk = Wqkv + ((size_t)(C_ + h * DH)) * C_;
    float* Ps = smb;
    float* Ks = smb + 32 * 97;

    for (int k0 = 0; k0 < C_; k0 += 32) {
        __syncthreads();
#pragma unroll
        for (int j = 0; j < 3; j++) {
            int f = tid + 256 * j;
            int row = f >> 3, q = f & 7;
            float4 v = *(const float4*)(P1 + (size_t)row * C_ + k0 + q * 4);
            Ps[(q * 4 + 0) * 97 + row] = v.x;
            Ps[(q * 4 + 1) * 97 + row] = v.y;
            Ps[(q * 4 + 2) * 97 + row] = v.z;
            Ps[(q * 4 + 3) * 97 + row] = v.w;
            float4 w = *(const float4*)(Wk + (size_t)row * C_ + k0 + q * 4);
            Ks[(q * 4 + 0) * 97 + row] = w.x;
            Ks[(q * 4 + 1) * 97 + row] = w.y;
            Ks[(q * 4 + 2) * 97 + row] = w.z;
            Ks[(q * 4 + 3) * 97 + row] = w.w;
        }
        __syncthreads();
#pragma unroll
        for (int k = 0; k < 32; k++) {
            float a[6], bb[6];
#pragma unroll
            for (int i = 0; i < 6; i++) a[i]  = Ps[k * 97 + ti * 6 + i];
#pragma unroll
            for (int j = 0; j < 6; j++) bb[j] = Ks[k * 97 + tj * 6 + j];
#pragma unroll
            for (int i = 0; i < 6; i++)
#pragma unroll
                for (int j = 0; j < 6; j++)
                    acc[i][j] = fmaf(a[i], bb[j], acc[i][j]);
        }
    }
    float tpr = temp[h];
    float nq[6], nk[6];
#pragma unroll
    for (int i = 0; i < 6; i++)
        nq[i] = fmaxf(sqrtf(ssq[b * C_ + h * DH + ti * 6 + i]), 1e-12f);
#pragma unroll
    for (int j = 0; j < 6; j++)
        nk[j] = fmaxf(sqrtf(ssq[B_ * C_ + b * C_ + h * DH + tj * 6 + j]), 1e-12f);
    __syncthreads();
#pragma unroll
    for (int i = 0; i < 6; i++)
#pragma unroll
        for (int j = 0; j < 6; j++)
            smb[(ti * 6 + i) * 97 + tj * 6 + j] = acc[i][j] / (nq[i] * nk[j]) * tpr;
    __syncthreads();
    if (tid < DH) {
        float* row = smb + tid * 97;
        float m = -1e30f;
        for (int d = 0; d < DH; d++) m = fmaxf(m, row[d]);
        float ssum = 0.f;
        for (int d = 0; d < DH; d++) { float ev = __expf(row[d] - m); row[d] = ev; ssum += ev; }
        float inv = 1.f / ssum;
        float* arow = attn + ((size_t)bh * DH + tid) * DH;
        for (int d = 0; d < DH; d++) arow[d] = row[d] * inv;
    }
}

__global__ __launch_bounds__(128) void k_T(const float* __restrict__ attn,
                                           const float* __restrict__ Wqkv,
                                           float* __restrict__ T) {
    const int ck = blockIdx.x * 128 + threadIdx.x;
    const int y = blockIdx.y;
    const int b = y / C_, hc = y % C_, h = hc / DH, c = hc % DH;
    const float* ar = attn + ((size_t)(b * NH + h) * DH + c) * DH;
    const float* wv = Wqkv + ((size_t)(2 * C_ + h * DH)) * C_ + ck;
    float s = 0.f;
#pragma unroll 8
    for (int d = 0; d < DH; d++) s = fmaf(ar[d], wv[(size_t)d * C_], s);
    T[((size_t)b * C_ + hc) * C_ + ck] = s;
}

__global__ __launch_bounds__(256, 2) void k_Mp(const float* __restrict__ Wout,
                                               const float* __restrict__ T,
                                               float* __restrict__ Mp) {
    __shared__ float As[16][132];
    __shared__ float Bs[16][132];
    const int tid = threadIdx.x;
    const int b = blockIdx.z;
    const int m0 = blockIdx.x * 128, n0 = blockIdx.y * 128;
    const int lr = tid >> 1, lk = (tid & 1) * 8;
    const int rt = tid >> 4, rc8 = (tid & 15) * 8;
    const int tm = (tid & 15) * 8, tn = (tid >> 4) * 8;
    const float* Tb = T + (size_t)b * C_ * C_;
    float acc[8][8];
#pragma unroll
    for (int i = 0; i < 8; i++)
#pragma unroll
        for (int j = 0; j < 8; j++) acc[i][j] = 0.f;

    for (int k0 = 0; k0 < C_; k0 += 16) {
        float4 a0 = *(const float4*)(Wout + (size_t)(m0 + lr) * C_ + k0 + lk);
        float4 a1 = *(const float4*)(Wout + (size_t)(m0 + lr) * C_ + k0 + lk + 4);
        float4 b0 = *(const float4*)(Tb + (size_t)(k0 + rt) * C_ + n0 + rc8);
        float4 b1 = *(const float4*)(Tb + (size_t)(k0 + rt) * C_ + n0 + rc8 + 4);
        __syncthreads();
        As[lk + 0][lr] = a0.x; As[lk + 1][lr] = a0.y; As[lk + 2][lr] = a0.z; As[lk + 3][lr] = a0.w;
        As[lk + 4][lr] = a1.x; As[lk + 5][lr] = a1.y; As[lk + 6][lr] = a1.z; As[lk + 7][lr] = a1.w;
        *(float4*)&Bs[rt][rc8]     = b0;
        *(float4*)&Bs[rt][rc8 + 4] = b1;
        __syncthreads();
#pragma unroll
        for (int k = 0; k < 16; k++) {
            float a[8], bb[8];
            *(float4*)&a[0]  = *(const float4*)&As[k][tm];
            *(float4*)&a[4]  = *(const float4*)&As[k][tm + 4];
            *(float4*)&bb[0] = *(const float4*)&Bs[k][tn];
            *(float4*)&bb[4] = *(const float4*)&Bs[k][tn + 4];
#pragma unroll
            for (int i = 0; i < 8; i++)
#pragma unroll
                for (int j = 0; j < 8; j++)
                    acc[i][j] = fmaf(a[i], bb[j], acc[i][j]);
        }
    }
    float* outp = Mp + ((size_t)b * C_ + m0 + tm) * C_ + n0 + tn;
#pragma unroll
    for (int i = 0; i < 8; i++) {
        float4 c0 = make_float4(acc[i][0], acc[i][1], acc[i][2], acc[i][3]);
        float4 c1 = make_float4(acc[i][4], acc[i][5], acc[i][6], acc[i][7]);
        *(float4*)(outp + (size_t)i * C_)     = c0;
        *(float4*)(outp + (size_t)i * C_ + 4) = c1;
    }
}

// ---- round-1 fallback big kernels ----
__global__ __launch_bounds__(256, 2) void k_gram_f32(const float* __restrict__ X,
                                                     float* __restrict__ G) {
    __shared__ float Aa[16][132];
    __shared__ float Ab[16][132];
    const int tid = threadIdx.x;
    const int chunk = blockIdx.x;
    const int ti = blockIdx.y / 3, tj = blockIdx.y % 3;
    const int b = blockIdx.z;
    const int t  = tid >> 4;
    const int c8 = (tid & 15) * 8;
    const int tm = (tid & 15) * 8, tn = (tid >> 4) * 8;
    float acc[8][8];
#pragma unroll
    for (int i = 0; i < 8; i++)
#pragma unroll
        for (int j = 0; j < 8; j++) acc[i][j] = 0.f;

    const float* Xb = X + ((size_t)b * NTOK + (size_t)chunk * 1024) * C_;
    for (int s = 0; s < 1024; s += 16) {
        const float* xr = Xb + (size_t)(s + t) * C_;
        float4 a0 = *(const float4*)(xr + ti * 128 + c8);
        float4 a1 = *(const float4*)(xr + ti * 128 + c8 + 4);
        float4 b0 = *(const float4*)(xr + tj * 128 + c8);
        float4 b1 = *(const float4*)(xr + tj * 128 + c8 + 4);
        __syncthreads();
        *(float4*)&Aa[t][c8]     = a0;
        *(float4*)&Aa[t][c8 + 4] = a1;
        *(float4*)&Ab[t][c8]     = b0;
        *(float4*)&Ab[t][c8 + 4] = b1;
        __syncthreads();
#pragma unroll
        for (int k = 0; k < 16; k++) {
            float a[8], bb[8];
            *(float4*)&a[0]  = *(const float4*)&Aa[k][tm];
            *(float4*)&a[4]  = *(const float4*)&Aa[k][tm + 4];
            *(float4*)&bb[0] = *(const float4*)&Ab[k][tn];
            *(float4*)&bb[4] = *(const float4*)&Ab[k][tn + 4];
#pragma unroll
            for (int i = 0; i < 8; i++)
#pragma unroll
                for (int j = 0; j < 8; j++)
                    acc[i][j] = fmaf(a[i], bb[j], acc[i][j]);
        }
    }
    float* Gb = G + (size_t)b * C_ * C_;
#pragma unroll
    for (int i = 0; i < 8; i++)
#pragma unroll
        for (int j = 0; j < 8; j++)
            atomicAdd(&Gb[(size_t)(ti * 128 + tm + i) * C_ + tj * 128 + tn + j],
                      acc[i][j]);
}

__global__ __launch_bounds__(256, 2) void k_out_f32(const float* __restrict__ X,
                                                    const float* __restrict__ Mp,
                                                    const float* __restrict__ bias,
                                                    float* __restrict__ out) {
    __shared__ float As[16][132];
    __shared__ float Bs[16][132];
    const int tid = threadIdx.x;
    const int m0 = blockIdx.x * 128, n0 = blockIdx.y * 128;
    const int b = m0 / NTOK;
    const float* Mb = Mp + (size_t)b * C_ * C_;
    const int lr = tid >> 1, lk = (tid & 1) * 8;
    const int tm = (tid & 15) * 8, tn = (tid >> 4) * 8;
    float acc[8][8];
#pragma unroll
    for (int i = 0; i < 8; i++)
#pragma unroll
        for (int j = 0; j < 8; j++) acc[i][j] = 0.f;

    for (int k0 = 0; k0 < C_; k0 += 16) {
        float4 a0 = *(const float4*)(X  + (size_t)(m0 + lr) * C_ + k0 + lk);
        float4 a1 = *(const float4*)(X  + (size_t)(m0 + lr) * C_ + k0 + lk + 4);
        float4 b0 = *(const float4*)(Mb + (size_t)(n0 + lr) * C_ + k0 + lk);
        float4 b1 = *(const float4*)(Mb + (size_t)(n0 + lr) * C_ + k0 + lk + 4);
        __syncthreads();
        As[lk + 0][lr] = a0.x; As[lk + 1][lr] = a0.y; As[lk + 2][lr] = a0.z; As[lk + 3][lr] = a0.w;
        As[lk + 4][lr] = a1.x; As[lk + 5][lr] = a1.y; As[lk + 6][lr] = a1.z; As[lk + 7][lr] = a1.w;
        Bs[lk + 0][lr] = b0.x; Bs[lk + 1][lr] = b0.y; Bs[lk + 2][lr] = b0.z; Bs[lk + 3][lr] = b0.w;
        Bs[lk + 4][lr] = b1.x; Bs[lk + 5][lr] = b1.y; Bs[lk + 6][lr] = b1.z; Bs[lk + 7][lr] = b1.w;
        __syncthreads();
#pragma unroll
        for (int k = 0; k < 16; k++) {
            float a[8], bb[8];
            *(float4*)&a[0]  = *(const float4*)&As[k][tm];
            *(float4*)&a[4]  = *(const float4*)&As[k][tm + 4];
            *(float4*)&bb[0] = *(const float4*)&Bs[k][tn];
            *(float4*)&bb[4] = *(const float4*)&Bs[k][tn + 4];
#pragma unroll
            for (int i = 0; i < 8; i++)
#pragma unroll
                for (int j = 0; j < 8; j++)
                    acc[i][j] = fmaf(a[i], bb[j], acc[i][j]);
        }
    }
#pragma unroll
    for (int i = 0; i < 8; i++) {
        float4 c0 = make_float4(acc[i][0] + bias[n0 + tn + 0],
                                acc[i][1] + bias[n0 + tn + 1],
                                acc[i][2] + bias[n0 + tn + 2],
                                acc[i][3] + bias[n0 + tn + 3]);
        float4 c1 = make_float4(acc[i][4] + bias[n0 + tn + 4],
                                acc[i][5] + bias[n0 + tn + 5],
                                acc[i][6] + bias[n0 + tn + 6],
                                acc[i][7] + bias[n0 + tn + 7]);
        float* row = out + (size_t)(m0 + tm + i) * C_ + n0 + tn;
        *(float4*)row       = c0;
        *(float4*)(row + 4) = c1;
    }
}

extern "C" void kernel_launch(void* const* d_in, const int* in_sizes, int n_in,
                              void* d_out, int out_size, void* d_ws, size_t ws_size,
                              hipStream_t stream) {
    const float* x    = (const float*)d_in[0];
    const float* Wqkv = (const float*)d_in[1];
    const float* temp = (const float*)d_in[2];
    const float* Wout = (const float*)d_in[3];
    const float* bout = (const float*)d_in[4];
    float* out = (float*)d_out;

    if (ws_size >= WS_NEED) {
        unsigned char* w8 = (unsigned char*)d_ws;
        unsigned short* Xh  = (unsigned short*)(w8 + XH_B);
        unsigned short* XhT = (unsigned short*)(w8 + XHT_B);
        float* Gpart = (float*)(w8 + GP_B);
        float* G     = (float*)(w8 + G_B);
        float* P     = (float*)(w8 + P_B);
        float* ssq   = (float*)(w8 + SSQ_B);
        float* att   = (float*)(w8 + ATT_B);
        float* T     = (float*)(w8 + T_B);
        float* Mp    = (float*)(w8 + MP_B);
        unsigned short* Mph = (unsigned short*)(w8 + MPH_B);

        k_conv     <<<dim3(256, 6, B_), 256, 0, stream>>>(x, Xh, XhT);
        k_gram_mfma<<<dim3(576), 256, 0, stream>>>(XhT, Gpart);
        k_reduceG  <<<dim3(576), 256, 0, stream>>>(Gpart, G);
        k_P        <<<dim3(3, 3, 2 * B_), 256, 0, stream>>>(Wqkv, G, P);
        k_diag     <<<dim3(12), 256, 0, stream>>>(P, Wqkv, ssq);
        k_attn     <<<dim3(B_ * NH), 256, 0, stream>>>(P, Wqkv, ssq, temp, att);
        k_T        <<<dim3(3, B_ * C_), 128, 0, stream>>>(att, Wqkv, T);
        k_Mp       <<<dim3(3, 3, B_), 256, 0, stream>>>(Wout, T, Mp);
        k_convM    <<<dim3(576), 256, 0, stream>>>(Mp, Mph);
        k_out_mfma <<<dim3(1536), 256, 0, stream>>>(Xh, Mph, bout, out);
    } else {
        float* ws  = (float*)d_ws;
        float* G    = ws + FG_OFF;
        float* P    = ws + FP_OFF;
        float* ssq  = ws + FSSQ_OFF;
        float* att  = ws + FATT_OFF;
        float* T    = ws + FT_OFF;
        float* Mp   = ws + FMP_OFF;

        k_zero    <<<dim3(FG_SZ / 256), 256, 0, stream>>>(G, FG_SZ);
        k_gram_f32<<<dim3(16, 9, B_), 256, 0, stream>>>(x, G);
        k_P       <<<dim3(3, 3, 2 * B_), 256, 0, stream>>>(Wqkv, G, P);
        k_diag    <<<dim3(12), 256, 0, stream>>>(P, Wqkv, ssq);
        k_attn    <<<dim3(B_ * NH), 256, 0, stream>>>(P, Wqkv, ssq, temp, att);
        k_T       <<<dim3(3, B_ * C_), 128, 0, stream>>>(att, Wqkv, T);
        k_Mp      <<<dim3(3, 3, B_), 256, 0, stream>>>(Wout, T, Mp);
        k_out_f32 <<<dim3(NTOK * B_ / 128, 3), 256, 0, stream>>>(x, Mp, bout, out);
    }
}

// Round 5
// 409.004 us; speedup vs baseline: 2.4299x; 1.1567x over previous
//
#include <hip/hip_runtime.h>
#include <math.h>

// ============================================================================
// ChannelAttention — Gram restructure, bf16 MFMA big GEMMs, re-tiled fp32
// small chain (64x64 tiles / 4x4 microtiles for occupancy).
//
//   k_conv:   X(fp32) -> Xh [b][t][c] bf16  and  XhT [b][c][t] bf16
//   k_gram:   Gpart[chunk] = XhT-tile @ XhT-tile^T (MFMA, no atomics)
//   k_reduce: G = sum_chunk Gpart
//   k_P64:    P[sel][b] = W_{q|k} @ G_b          (288 blocks)
//   k_diag:   ssq = row-dots (q/k squared norms)
//   k_S:      S[b][h] = head-diag blocks of P1 Wk^T   (96 blocks)
//   k_soft:   S -> attn (normalize, *temp, softmax) in-place
//   k_T:      T_b = blockdiag(attn) @ Wv
//   k_Mp64:   Mph = bf16(W_out @ T_b)            (144 blocks, fused convert)
//   k_out:    out = Xh @ Mph^T + bias (MFMA)
// ============================================================================

#define B_    4
#define NTOK  16384
#define C_    384
#define NH    4
#define DH    96

typedef __attribute__((ext_vector_type(8))) short short8;
typedef __attribute__((ext_vector_type(4))) float f32x4;
typedef __attribute__((ext_vector_type(4))) unsigned short ushort4v;
typedef __attribute__((ext_vector_type(8))) unsigned short ushort8v;

// ---- ws byte offsets (ws = 384 MiB confirmed round 3) ----
#define XH_B   0ull
#define XHT_B  50331648ull            // + B*N*C*2
#define GP_B   100663296ull           // 16 chunk partials x 4 batches, fp32
#define G_B    138412032ull
#define P_B    140771328ull
#define SSQ_B  145489920ull
#define ATT_B  145502208ull           // S, then attn in-place (16*96*96 f32)
#define T_B    146092032ull           // T (4*384*384 f32)
#define MPH_B  150810624ull

__device__ inline unsigned short f2bf(float f) {
    unsigned u = __float_as_uint(f);
    u += 0x7FFFu + ((u >> 16) & 1u);          // RNE
    return (unsigned short)(u >> 16);
}

__device__ inline void load16(const void* g, void* l) {
    __builtin_amdgcn_global_load_lds(
        (const __attribute__((address_space(1))) unsigned int*)g,
        (__attribute__((address_space(3))) unsigned int*)l, 16, 0, 0);
}

// ---------------------------------------------------------------------------
// X fp32 -> Xh (natural) + XhT (transposed) bf16.  64x64 tiles via LDS.
// ---------------------------------------------------------------------------
__global__ __launch_bounds__(256) void k_conv(const float* __restrict__ X,
                                              unsigned short* __restrict__ Xh,
                                              unsigned short* __restrict__ XhT) {
    __shared__ __align__(16) unsigned short Th[64][72];
    const int tid = threadIdx.x;
    const int t0 = blockIdx.x * 64, c0 = blockIdx.y * 64, b = blockIdx.z;
    const int tl0 = tid >> 4, cl = (tid & 15) * 4;
#pragma unroll
    for (int p = 0; p < 4; ++p) {
        const int t = t0 + tl0 + p * 16;
        const float4 v = *(const float4*)(X + ((size_t)(b * NTOK + t)) * C_ + c0 + cl);
        const unsigned short h0 = f2bf(v.x), h1 = f2bf(v.y), h2 = f2bf(v.z), h3 = f2bf(v.w);
        ushort4v hv; hv.x = h0; hv.y = h1; hv.z = h2; hv.w = h3;
        *(ushort4v*)(Xh + ((size_t)(b * NTOK + t)) * C_ + c0 + cl) = hv;
        const int tl = tl0 + p * 16;
        Th[cl + 0][tl] = h0; Th[cl + 1][tl] = h1; Th[cl + 2][tl] = h2; Th[cl + 3][tl] = h3;
    }
    __syncthreads();
    const int c = tid >> 2, seg = (tid & 3) * 16;
    const ushort8v a  = *(const ushort8v*)&Th[c][seg];
    const ushort8v bb = *(const ushort8v*)&Th[c][seg + 8];
    unsigned short* dst = XhT + ((size_t)(b * C_ + c0 + c)) * NTOK + t0 + seg;
    *(ushort8v*)dst       = a;
    *(ushort8v*)(dst + 8) = bb;
}

// ---------------------------------------------------------------------------
// Gpart[grp] tile(i,j) 128x128 over a 1024-token chunk.  MFMA 16x16x32 bf16.
// ---------------------------------------------------------------------------
__global__ __launch_bounds__(256, 2) void k_gram_mfma(const unsigned short* __restrict__ XhT,
                                                      float* __restrict__ Gpart) {
    __shared__ __align__(16) unsigned char sm[32768];
    const int l = blockIdx.x;
    const int xcd = l & 7, slot = l >> 3;
    const int grp = xcd * 8 + slot / 9, tile = slot % 9;
    const int chunk = grp >> 2, b = grp & 3;
    const int ti = tile / 3, tj = tile % 3;
    const int tid = threadIdx.x;
    const int lane = tid & 63, wid = tid >> 6;
    const int wr = wid >> 1, wc = wid & 1;

    const int e = (lane & 7) ^ (lane >> 3);   // inverse-swizzled source slot
    const int rsub = lane >> 3;

    const size_t rowb = (size_t)NTOK * 2;
    const unsigned char* Abase = (const unsigned char*)XhT + (size_t)(b * C_ + ti * 128) * rowb;
    const unsigned char* Bbase = (const unsigned char*)XhT + (size_t)(b * C_ + tj * 128) * rowb;

    f32x4 acc[4][4];
#pragma unroll
    for (int i = 0; i < 4; i++)
#pragma unroll
        for (int j = 0; j < 4; j++) acc[i][j] = (f32x4)(0.f);

    for (int ks = 0; ks < 16; ++ks) {
        const size_t colb = (size_t)(chunk * 1024 + ks * 64) * 2 + (size_t)e * 16;
        __syncthreads();
#pragma unroll
        for (int call = 0; call < 4; ++call) {
            const int row = wid * 32 + call * 8 + rsub;
            load16(Abase + (size_t)row * rowb + colb, sm + (wid * 32 + call * 8) * 128);
            load16(Bbase + (size_t)row * rowb + colb, sm + 16384 + (wid * 32 + call * 8) * 128);
        }
        __syncthreads();
#pragma unroll
        for (int p = 0; p < 2; ++p) {
            const int s = p * 4 + (lane >> 4);
            short8 av[4], bv[4];
#pragma unroll
            for (int fi = 0; fi < 4; ++fi) {
                const int c = wr * 64 + fi * 16 + (lane & 15);
                av[fi] = *(const short8*)(sm + c * 128 + ((s ^ (c & 7)) << 4));
            }
#pragma unroll
            for (int fj = 0; fj < 4; ++fj) {
                const int c = wc * 64 + fj * 16 + (lane & 15);
                bv[fj] = *(const short8*)(sm + 16384 + c * 128 + ((s ^ (c & 7)) << 4));
            }
#pragma unroll
            for (int fi = 0; fi < 4; ++fi)
#pragma unroll
                for (int fj = 0; fj < 4; ++fj)
                    acc[fi][fj] = __builtin_amdgcn_mfma_f32_16x16x32_bf16(av[fi], bv[fj], acc[fi][fj], 0, 0, 0);
        }
    }
    float* gp = Gpart + (size_t)grp * (C_ * C_);
    const int r0 = (lane >> 4) * 4, cc = lane & 15;
#pragma unroll
    for (int fi = 0; fi < 4; ++fi) {
        const int ci = ti * 128 + wr * 64 + fi * 16 + r0;
#pragma unroll
        for (int fj = 0; fj < 4; ++fj) {
            const int cj = tj * 128 + wc * 64 + fj * 16 + cc;
#pragma unroll
            for (int r = 0; r < 4; ++r)
                gp[(size_t)(ci + r) * C_ + cj] = acc[fi][fj][r];
        }
    }
}

__global__ __launch_bounds__(256) void k_reduceG(const float* __restrict__ Gpart,
                                                 float* __restrict__ G) {
    const size_t eo = ((size_t)blockIdx.x * 256 + threadIdx.x) * 4;
    float4 s = *(const float4*)(Gpart + eo);
#pragma unroll
    for (int c = 1; c < 16; ++c) {
        const float4 v = *(const float4*)(Gpart + (size_t)c * (B_ * C_ * C_) + eo);
        s.x += v.x; s.y += v.y; s.z += v.z; s.w += v.w;
    }
    *(float4*)(G + eo) = s;
}

// ---------------------------------------------------------------------------
// P[sel][b][m][n] = sum_k W_sel[m][k] * G_b[n][k]   (G symmetric)
// 64x64 tiles, 4x4 microtile.  grid (6,6,8), 256 threads.
// ---------------------------------------------------------------------------
__global__ __launch_bounds__(256) void k_P64(const float* __restrict__ Wqkv,
                                             const float* __restrict__ G,
                                             float* __restrict__ P) {
    __shared__ float As[32][65];
    __shared__ float Bs[32][65];
    const int tid = threadIdx.x;
    const int sel = blockIdx.z & 1, b = blockIdx.z >> 1;
    const int m0 = blockIdx.x * 64, n0 = blockIdx.y * 64;
    const float* A  = Wqkv + (size_t)sel * C_ * C_;
    const float* Bm = G + (size_t)b * C_ * C_;
    const int lr = tid >> 2, lk = (tid & 3) * 8;
    const int tm = (tid & 15) * 4, tn = (tid >> 4) * 4;
    float acc[4][4];
#pragma unroll
    for (int i = 0; i < 4; i++)
#pragma unroll
        for (int j = 0; j < 4; j++) acc[i][j] = 0.f;

    for (int k0 = 0; k0 < C_; k0 += 32) {
        float4 a0 = *(const float4*)(A  + (size_t)(m0 + lr) * C_ + k0 + lk);
        float4 a1 = *(const float4*)(A  + (size_t)(m0 + lr) * C_ + k0 + lk + 4);
        float4 b0 = *(const float4*)(Bm + (size_t)(n0 + lr) * C_ + k0 + lk);
        float4 b1 = *(const float4*)(Bm + (size_t)(n0 + lr) * C_ + k0 + lk + 4);
        __syncthreads();
        As[lk + 0][lr] = a0.x; As[lk + 1][lr] = a0.y; As[lk + 2][lr] = a0.z; As[lk + 3][lr] = a0.w;
        As[lk + 4][lr] = a1.x; As[lk + 5][lr] = a1.y; As[lk + 6][lr] = a1.z; As[lk + 7][lr] = a1.w;
        Bs[lk + 0][lr] = b0.x; Bs[lk + 1][lr] = b0.y; Bs[lk + 2][lr] = b0.z; Bs[lk + 3][lr] = b0.w;
        Bs[lk + 4][lr] = b1.x; Bs[lk + 5][lr] = b1.y; Bs[lk + 6][lr] = b1.z; Bs[lk + 7][lr] = b1.w;
        __syncthreads();
#pragma unroll
        for (int k = 0; k < 32; k++) {
            float a[4], bb[4];
            *(float4*)&a[0]  = *(const float4*)&As[k][tm];
            *(float4*)&bb[0] = *(const float4*)&Bs[k][tn];
#pragma unroll
            for (int i = 0; i < 4; i++)
#pragma unroll
                for (int j = 0; j < 4; j++)
                    acc[i][j] = fmaf(a[i], bb[j], acc[i][j]);
        }
    }
    float* outp = P + ((size_t)(sel * B_ + b) * C_ + m0 + tm) * C_ + n0 + tn;
#pragma unroll
    for (int i = 0; i < 4; i++) {
        float4 c0 = make_float4(acc[i][0], acc[i][1], acc[i][2], acc[i][3]);
        *(float4*)(outp + (size_t)i * C_) = c0;
    }
}

// ---------------------------------------------------------------------------
// ssq[sel][b][c] = <P[sel][b][c][:], W_{sel}[c][:]>
// ---------------------------------------------------------------------------
__global__ __launch_bounds__(256) void k_diag(const float* __restrict__ P,
                                              const float* __restrict__ Wqkv,
                                              float* __restrict__ ssq) {
    int g = blockIdx.x * 256 + threadIdx.x;
    int sel = g / (B_ * C_), rem = g % (B_ * C_), b = rem / C_, c = rem % C_;
    const float* pr = P + ((size_t)(sel * B_ + b) * C_ + c) * C_;
    const float* wr = Wqkv + ((size_t)sel * C_ + c) * C_;
    float s = 0.f;
#pragma unroll 4
    for (int k = 0; k < C_; k += 4) {
        float4 pv = *(const float4*)(pr + k);
        float4 wv = *(const float4*)(wr + k);
        s += pv.x * wv.x + pv.y * wv.y + pv.z * wv.z + pv.w * wv.w;
    }
    ssq[g] = s;
}

// ---------------------------------------------------------------------------
// S[bh][r][c] = sum_k P1[b][h*96+r][k] * Wk[h*96+c][k]
// grid (6 col-strips of 16, 16 bh), 256 threads; 6 rows x 1 col per thread.
// ---------------------------------------------------------------------------
__global__ __launch_bounds__(256) void k_S(const float* __restrict__ P,
                                           const float* __restrict__ Wqkv,
                                           float* __restrict__ S) {
    __shared__ float Ps[32 * 97];
    __shared__ float Ks[32 * 17];
    const int cs = blockIdx.x, bh = blockIdx.y;
    const int b = bh >> 2, h = bh & 3;
    const int tid = threadIdx.x;
    const int ti = tid & 15, tj = tid >> 4;
    const float* P1 = P + ((size_t)b * C_ + h * DH) * C_;
    const float* Wk = Wqkv + ((size_t)(C_ + h * DH + cs * 16)) * C_;
    float acc[6];
#pragma unroll
    for (int i = 0; i < 6; i++) acc[i] = 0.f;

    for (int k0 = 0; k0 < C_; k0 += 32) {
        __syncthreads();
#pragma unroll
        for (int j = 0; j < 3; j++) {
            int f = tid + 256 * j;
            int row = f >> 3, q = f & 7;
            float4 v = *(const float4*)(P1 + (size_t)row * C_ + k0 + q * 4);
            Ps[(q * 4 + 0) * 97 + row] = v.x;
            Ps[(q * 4 + 1) * 97 + row] = v.y;
            Ps[(q * 4 + 2) * 97 + row] = v.z;
            Ps[(q * 4 + 3) * 97 + row] = v.w;
        }
        {
            int row = tid >> 4, kk = (tid & 15) * 2;
            float2 w = *(const float2*)(Wk + (size_t)row * C_ + k0 + kk);
            Ks[(kk + 0) * 17 + row] = w.x;
            Ks[(kk + 1) * 17 + row] = w.y;
        }
        __syncthreads();
#pragma unroll
        for (int k = 0; k < 32; k++) {
            const float bb = Ks[k * 17 + tj];
#pragma unroll
            for (int i = 0; i < 6; i++)
                acc[i] = fmaf(Ps[k * 97 + ti * 6 + i], bb, acc[i]);
        }
    }
    float* Sb = S + (size_t)bh * DH * DH;
#pragma unroll
    for (int i = 0; i < 6; i++)
        Sb[(size_t)(ti * 6 + i) * DH + cs * 16 + tj] = acc[i];
}

// ---------------------------------------------------------------------------
// S -> attn in place: row r scaled by temp/(nq[r]*nk[c]) then softmax over c.
// grid (16), 128 threads (96 active rows).
// ---------------------------------------------------------------------------
__global__ __launch_bounds__(128) void k_soft(float* __restrict__ S,
                                              const float* __restrict__ ssq,
                                              const float* __restrict__ temp) {
    __shared__ float rnk[DH];
    const int bh = blockIdx.x;
    const int b = bh >> 2, h = bh & 3;
    const int r = threadIdx.x;
    if (r < DH)
        rnk[r] = 1.f / fmaxf(sqrtf(ssq[B_ * C_ + b * C_ + h * DH + r]), 1e-12f);
    __syncthreads();
    if (r >= DH) return;
    const float rnq = temp[h] / fmaxf(sqrtf(ssq[b * C_ + h * DH + r]), 1e-12f);
    float* row = S + (size_t)bh * DH * DH + (size_t)r * DH;
    float rv[DH];
    float m = -1e30f;
#pragma unroll
    for (int d = 0; d < DH; d++) {
        rv[d] = row[d] * rnq * rnk[d];
        m = fmaxf(m, rv[d]);
    }
    float s = 0.f;
#pragma unroll
    for (int d = 0; d < DH; d++) { rv[d] = __expf(rv[d] - m); s += rv[d]; }
    const float inv = 1.f / s;
#pragma unroll
    for (int d = 0; d < DH; d++) row[d] = rv[d] * inv;
}

// ---------------------------------------------------------------------------
// T_b[(h,c)][ck] = sum_d attn[b][h][c][d] * Wv[(h,d)][ck]
// ---------------------------------------------------------------------------
__global__ __launch_bounds__(128) void k_T(const float* __restrict__ attn,
                                           const float* __restrict__ Wqkv,
                                           float* __restrict__ T) {
    const int ck = blockIdx.x * 128 + threadIdx.x;
    const int y = blockIdx.y;
    const int b = y / C_, hc = y % C_, h = hc / DH, c = hc % DH;
    const float* ar = attn + ((size_t)(b * NH + h) * DH + c) * DH;
    const float* wv = Wqkv + ((size_t)(2 * C_ + h * DH)) * C_ + ck;
    float s = 0.f;
#pragma unroll 8
    for (int d = 0; d < DH; d++) s = fmaf(ar[d], wv[(size_t)d * C_], s);
    T[((size_t)b * C_ + hc) * C_ + ck] = s;
}

// ---------------------------------------------------------------------------
// Mph[b][m][n] = bf16( sum_k Wout[m][k] * T_b[k][n] )
// 64x64 tiles, 4x4 microtile.  grid (6,6,4), 256 threads.
// ---------------------------------------------------------------------------
__global__ __launch_bounds__(256) void k_Mp64(const float* __restrict__ Wout,
                                              const float* __restrict__ T,
                                              unsigned short* __restrict__ Mph) {
    __shared__ float As[32][65];
    __shared__ float Bs[32][65];
    const int tid = threadIdx.x;
    const int b = blockIdx.z;
    const int m0 = blockIdx.x * 64, n0 = blockIdx.y * 64;
    const float* Tb = T + (size_t)b * C_ * C_;
    const int la_r = tid >> 2, la_k = (tid & 3) * 8;
    const int lb_k = tid >> 3, lb_c = (tid & 7) * 8;
    const int tm = (tid & 15) * 4, tn = (tid >> 4) * 4;
    float acc[4][4];
#pragma unroll
    for (int i = 0; i < 4; i++)
#pragma unroll
        for (int j = 0; j < 4; j++) acc[i][j] = 0.f;

    for (int k0 = 0; k0 < C_; k0 += 32) {
        float4 a0 = *(const float4*)(Wout + (size_t)(m0 + la_r) * C_ + k0 + la_k);
        float4 a1 = *(const float4*)(Wout + (size_t)(m0 + la_r) * C_ + k0 + la_k + 4);
        float4 b0 = *(const float4*)(Tb + (size_t)(k0 + lb_k) * C_ + n0 + lb_c);
        float4 b1 = *(const float4*)(Tb + (size_t)(k0 + lb_k) * C_ + n0 + lb_c + 4);
        __syncthreads();
        As[la_k + 0][la_r] = a0.x; As[la_k + 1][la_r] = a0.y; As[la_k + 2][la_r] = a0.z; As[la_k + 3][la_r] = a0.w;
        As[la_k + 4][la_r] = a1.x; As[la_k + 5][la_r] = a1.y; As[la_k + 6][la_r] = a1.z; As[la_k + 7][la_r] = a1.w;
        *(float4*)&Bs[lb_k][lb_c]     = b0;
        *(float4*)&Bs[lb_k][lb_c + 4] = b1;
        __syncthreads();
#pragma unroll
        for (int k = 0; k < 32; k++) {
            float a[4], bb[4];
            *(float4*)&a[0]  = *(const float4*)&As[k][tm];
            *(float4*)&bb[0] = *(const float4*)&Bs[k][tn];
#pragma unroll
            for (int i = 0; i < 4; i++)
#pragma unroll
                for (int j = 0; j < 4; j++)
                    acc[i][j] = fmaf(a[i], bb[j], acc[i][j]);
        }
    }
    unsigned short* outp = Mph + ((size_t)b * C_ + m0 + tm) * C_ + n0 + tn;
#pragma unroll
    for (int i = 0; i < 4; i++) {
        ushort4v h4;
        h4.x = f2bf(acc[i][0]); h4.y = f2bf(acc[i][1]);
        h4.z = f2bf(acc[i][2]); h4.w = f2bf(acc[i][3]);
        *(ushort4v*)(outp + (size_t)i * C_) = h4;
    }
}

// ---------------------------------------------------------------------------
// out[m][i] = sum_ck Xh[m][ck]*Mph[b][i][ck] + bias[i].  MFMA, K=384.
// ---------------------------------------------------------------------------
__global__ __launch_bounds__(256, 2) void k_out_mfma(const unsigned short* __restrict__ Xh,
                                                     const unsigned short* __restrict__ Mph,
                                                     const float* __restrict__ bias,
                                                     float* __restrict__ out) {
    __shared__ __align__(16) unsigned char sm[32768];
    const int l = blockIdx.x;
    const int xcd = l & 7, k = l >> 3;
    const int mblk = xcd * 64 + k / 3, nblk = k % 3;
    const int m0 = mblk * 128, i0 = nblk * 128;
    const int b = mblk >> 7;
    const int tid = threadIdx.x;
    const int lane = tid & 63, wid = tid >> 6;
    const int wr = wid >> 1, wc = wid & 1;

    const int e = (lane & 7) ^ (lane >> 3);
    const int rsub = lane >> 3;

    const unsigned char* Abase = (const unsigned char*)Xh + (size_t)m0 * (C_ * 2);
    const unsigned char* Bbase = (const unsigned char*)Mph + (size_t)b * (C_ * C_ * 2) + (size_t)i0 * (C_ * 2);

    f32x4 acc[4][4];
#pragma unroll
    for (int i = 0; i < 4; i++)
#pragma unroll
        for (int j = 0; j < 4; j++) acc[i][j] = (f32x4)(0.f);

    for (int ks = 0; ks < 6; ++ks) {
        const size_t colb = (size_t)ks * 128 + (size_t)e * 16;
        __syncthreads();
#pragma unroll
        for (int call = 0; call < 4; ++call) {
            const int row = wid * 32 + call * 8 + rsub;
            load16(Abase + (size_t)row * (C_ * 2) + colb, sm + (wid * 32 + call * 8) * 128);
            load16(Bbase + (size_t)row * (C_ * 2) + colb, sm + 16384 + (wid * 32 + call * 8) * 128);
        }
        __syncthreads();
#pragma unroll
        for (int p = 0; p < 2; ++p) {
            const int s = p * 4 + (lane >> 4);
            short8 av[4], bv[4];
#pragma unroll
            for (int fi = 0; fi < 4; ++fi) {
                const int c = wr * 64 + fi * 16 + (lane & 15);
                av[fi] = *(const short8*)(sm + c * 128 + ((s ^ (c & 7)) << 4));
            }
#pragma unroll
            for (int fj = 0; fj < 4; ++fj) {
                const int c = wc * 64 + fj * 16 + (lane & 15);
                bv[fj] = *(const short8*)(sm + 16384 + c * 128 + ((s ^ (c & 7)) << 4));
            }
#pragma unroll
            for (int fi = 0; fi < 4; ++fi)
#pragma unroll
                for (int fj = 0; fj < 4; ++fj)
                    acc[fi][fj] = __builtin_amdgcn_mfma_f32_16x16x32_bf16(av[fi], bv[fj], acc[fi][fj], 0, 0, 0);
        }
    }
    const int r0 = (lane >> 4) * 4, cc = lane & 15;
#pragma unroll
    for (int fi = 0; fi < 4; ++fi) {
        const int m = m0 + wr * 64 + fi * 16 + r0;
#pragma unroll
        for (int fj = 0; fj < 4; ++fj) {
            const int ii = i0 + wc * 64 + fj * 16 + cc;
            const float bi = bias[ii];
#pragma unroll
            for (int r = 0; r < 4; ++r)
                out[(size_t)(m + r) * C_ + ii] = acc[fi][fj][r] + bi;
        }
    }
}

extern "C" void kernel_launch(void* const* d_in, const int* in_sizes, int n_in,
                              void* d_out, int out_size, void* d_ws, size_t ws_size,
                              hipStream_t stream) {
    const float* x    = (const float*)d_in[0];
    const float* Wqkv = (const float*)d_in[1];
    const float* temp = (const float*)d_in[2];
    const float* Wout = (const float*)d_in[3];
    const float* bout = (const float*)d_in[4];
    float* out = (float*)d_out;

    unsigned char* w8 = (unsigned char*)d_ws;
    unsigned short* Xh  = (unsigned short*)(w8 + XH_B);
    unsigned short* XhT = (unsigned short*)(w8 + XHT_B);
    float* Gpart = (float*)(w8 + GP_B);
    float* G     = (float*)(w8 + G_B);
    float* P     = (float*)(w8 + P_B);
    float* ssq   = (float*)(w8 + SSQ_B);
    float* Satt  = (float*)(w8 + ATT_B);
    float* T     = (float*)(w8 + T_B);
    unsigned short* Mph = (unsigned short*)(w8 + MPH_B);

    k_conv     <<<dim3(256, 6, B_), 256, 0, stream>>>(x, Xh, XhT);
    k_gram_mfma<<<dim3(576), 256, 0, stream>>>(XhT, Gpart);
    k_reduceG  <<<dim3(576), 256, 0, stream>>>(Gpart, G);
    k_P64      <<<dim3(6, 6, 2 * B_), 256, 0, stream>>>(Wqkv, G, P);
    k_diag     <<<dim3(12), 256, 0, stream>>>(P, Wqkv, ssq);
    k_S        <<<dim3(6, B_ * NH), 256, 0, stream>>>(P, Wqkv, Satt);
    k_soft     <<<dim3(B_ * NH), 128, 0, stream>>>(Satt, ssq, temp);
    k_T        <<<dim3(3, B_ * C_), 128, 0, stream>>>(Satt, Wqkv, T);
    k_Mp64     <<<dim3(6, 6, B_), 256, 0, stream>>>(Wout, T, Mph);
    k_out_mfma <<<dim3(1536), 256, 0, stream>>>(Xh, Mph, bout, out);
}